// Round 4
// baseline (67.118 us; speedup 1.0000x reference)
//
#include <hip/hip_runtime.h>

// B = 262144 rows, 256 -> 64 (relu) -> 16 (tanh) -> 4 -> global softmax.
// Layers 1-2 on MFMA f16 3-term split (xh*wh + xl*wh + xh*wl), pow2-scaled.
// x staged f32 via global_load_lds (src-side XOR swizzle), double-buffered,
// counted vmcnt; w1 fragments (hi+lo) persistent in registers.

typedef _Float16 half8 __attribute__((ext_vector_type(8)));
typedef float f32x4 __attribute__((ext_vector_type(4)));

#define GRID 256
#define TPB  512
#define TROWS 64

#define SCALE_IN 256.0f            // 2^8
#define SCALE_W  2048.0f           // 2^11
#define INV_SC   (1.0f/524288.0f)  // 2^-19

#define XBUF_BYTES 65536           // 64 rows x 256 f32 (row = 1 KiB, 64 chunks)
#define OFF_H1 (2*XBUF_BYTES)      // 131072: h1 f32 [64][68]
#define H1S 68
#define OFF_SUM (OFF_H1 + TROWS*H1S*4)   // 148480
#define SMEM_BYTES (OFF_SUM + 64)        // 148544 <= 163840

extern __shared__ char smem_raw[];

#define MFMA16(a,b,c) __builtin_amdgcn_mfma_f32_16x16x32_f16((a),(b),(c),0,0,0)

__device__ __forceinline__ void gload16(const float* g, float* l) {
    __builtin_amdgcn_global_load_lds(
        (const __attribute__((address_space(1))) void*)g,
        (__attribute__((address_space(3))) void*)l, 16, 0, 0);
}

// Stage one 64-row x tile; wave wid stages rows wid*8..wid*8+7 (1 row/instr).
// LDS content swizzle: LDS[r][chunk p] = x[r][chunk p ^ (r&7)]  (16B chunks).
// DMA writes LDS linearly (base + lane*16), so the XOR goes on the SOURCE.
__device__ __forceinline__ void stage_x(const float* xg_tile, char* xbuf,
                                        int wid, int lane) {
    #pragma unroll
    for (int j = 0; j < 8; ++j) {
        const int r = wid * 8 + j;                 // r & 7 == j
        const float* src = xg_tile + (size_t)r * 256 + ((lane ^ j) << 2);
        float* dst = (float*)(xbuf + r * 1024);
        gload16(src, dst);
    }
}

__device__ __forceinline__ void split8(const float* v, float scale,
                                       half8& h, half8& l) {
    #pragma unroll
    for (int j = 0; j < 8; ++j) {
        const float s = v[j] * scale;
        const _Float16 hi = (_Float16)s;
        h[j] = hi;
        l[j] = (_Float16)(s - (float)hi);
    }
}

__global__ __launch_bounds__(TPB, 2) void fused_mlp(
    const float* __restrict__ x,
    const float* __restrict__ wz1, const float* __restrict__ b1,
    const float* __restrict__ wz2, const float* __restrict__ b2,
    const float* __restrict__ wz3, const float* __restrict__ b3,
    float* __restrict__ Eout, float* __restrict__ block_sums,
    int ntiles)
{
    float* h1p  = (float*)(smem_raw + OFF_H1);
    float* sums = (float*)(smem_raw + OFF_SUM);

    const int tid  = threadIdx.x;
    const int lane = tid & 63;
    const int wid  = __builtin_amdgcn_readfirstlane(tid >> 6);
    const int l15  = lane & 15;
    const int g4   = lane >> 4;          // 0..3
    const int g8   = g4 * 8;

    const size_t blk_row0 = (size_t)blockIdx.x * ntiles * TROWS;

    // ---- prologue: issue x tile-0 DMA, then w1 DMA into xbuf[1] ----
    stage_x(x + blk_row0 * 256, smem_raw, wid, lane);
    {
        float* w1s = (float*)(smem_raw + XBUF_BYTES);
        #pragma unroll
        for (int j = 0; j < 8; ++j)
            gload16(wz1 + wid * 2048 + j * 256 + lane * 4,
                    w1s + wid * 2048 + j * 256);
    }

    // ---- per-lane constants & small-weight register fragments ----
    const int rt   = wid >> 1;           // row-tile 0..3
    const int ntp  = wid & 1;            // col-pair 0..1
    const int col0 = ntp * 32 + l15;
    const int col1 = col0 + 16;
    const float b1v0 = b1[col0], b1v1 = b1[col1];
    float b2v[4], w3v[4][4];
    #pragma unroll
    for (int i = 0; i < 4; ++i) {
        const int c2 = g4 * 4 + i;
        b2v[i] = b2[c2];
        #pragma unroll
        for (int c3 = 0; c3 < 4; ++c3) w3v[i][c3] = wz3[c2 * 4 + c3];
    }
    const float b3v[4] = {b3[0], b3[1], b3[2], b3[3]};

    half8 A2h[2], A2l[2];                // w2T fragments (layer 2 A-operand)
    #pragma unroll
    for (int kt = 0; kt < 2; ++kt) {
        float tmp[8];
        #pragma unroll
        for (int j = 0; j < 8; ++j) tmp[j] = wz2[(kt * 32 + g8 + j) * 16 + l15];
        split8(tmp, SCALE_W, A2h[kt], A2l[kt]);
    }

    asm volatile("s_waitcnt vmcnt(0)\ns_barrier" ::: "memory");

    // ---- build persistent w1 fragments (hi+lo) from LDS ----
    half8 Bh[8][2], Bl[8][2];
    {
        const float* w1s = (const float*)(smem_raw + XBUF_BYTES);
        #pragma unroll
        for (int kt = 0; kt < 8; ++kt) {
            float t0[8], t1[8];
            #pragma unroll
            for (int j = 0; j < 8; ++j) {
                const int k = kt * 32 + g8 + j;
                t0[j] = w1s[k * 64 + col0];
                t1[j] = w1s[k * 64 + col1];
            }
            split8(t0, SCALE_W, Bh[kt][0], Bl[kt][0]);
            split8(t1, SCALE_W, Bh[kt][1], Bl[kt][1]);
        }
    }
    asm volatile("s_waitcnt lgkmcnt(0)\ns_barrier" ::: "memory");  // xbuf[1] free

    const int arow = rt * 16 + l15;      // this lane's A-row within tile
    const int sw   = l15 & 7;            // read-side swizzle
    float local_sum = 0.f;

    for (int t = 0; t < ntiles; ++t) {
        const char* xb = smem_raw + (t & 1) * XBUF_BYTES;
        // issue next tile's DMA; keep its 8 loads in flight across barriers
        if (t + 1 < ntiles) {
            stage_x(x + (blk_row0 + (size_t)(t + 1) * TROWS) * 256,
                    smem_raw + ((t + 1) & 1) * XBUF_BYTES, wid, lane);
            asm volatile("s_waitcnt vmcnt(8)\ns_barrier" ::: "memory"); // B1
        } else {
            asm volatile("s_waitcnt vmcnt(0)\ns_barrier" ::: "memory"); // B1
        }

        // ---- layer 1: rows rt*16..+15, cols [ntp*32, +32), 3-term split ----
        f32x4 acc0 = {0.f, 0.f, 0.f, 0.f}, acc1 = {0.f, 0.f, 0.f, 0.f};
        {
            const char* xrow = xb + arow * 1024;
            #pragma unroll
            for (int kt = 0; kt < 8; ++kt) {
                const int c0 = kt * 8 + 2 * g4;
                const float4 lo = *(const float4*)(xrow + ((c0 ^ sw) << 4));
                const float4 hi = *(const float4*)(xrow + (((c0 + 1) ^ sw) << 4));
                const float v[8] = {lo.x, lo.y, lo.z, lo.w,
                                    hi.x, hi.y, hi.z, hi.w};
                half8 ah, al;
                split8(v, SCALE_IN, ah, al);
                acc0 = MFMA16(ah, Bh[kt][0], acc0);
                acc1 = MFMA16(ah, Bh[kt][1], acc1);
                acc0 = MFMA16(al, Bh[kt][0], acc0);
                acc1 = MFMA16(al, Bh[kt][1], acc1);
                acc0 = MFMA16(ah, Bl[kt][0], acc0);
                acc1 = MFMA16(ah, Bl[kt][1], acc1);
            }
        }
        // ---- epilogue: scale+bias+relu -> h1 (f32) ----
        #pragma unroll
        for (int i = 0; i < 4; ++i) {
            const int r = rt * 16 + g4 * 4 + i;
            h1p[r * H1S + col0] = fmaxf(fmaf(acc0[i], INV_SC, b1v0), 0.f);
            h1p[r * H1S + col1] = fmaxf(fmaf(acc1[i], INV_SC, b1v1), 0.f);
        }
        asm volatile("s_waitcnt lgkmcnt(0)\ns_barrier" ::: "memory");   // B2

        // ---- layer 2 (MFMA) + layer 3 + exp: waves 0..3 ----
        if (wid < 4) {
            const float* hrow = h1p + (wid * 16 + l15) * H1S;
            f32x4 a2 = {0.f, 0.f, 0.f, 0.f};
            #pragma unroll
            for (int kt = 0; kt < 2; ++kt) {
                const int k0 = kt * 32 + g8;
                const float4 lo = *(const float4*)(hrow + k0);
                const float4 hi = *(const float4*)(hrow + k0 + 4);
                const float v[8] = {lo.x, lo.y, lo.z, lo.w,
                                    hi.x, hi.y, hi.z, hi.w};
                half8 bh, bl;
                split8(v, SCALE_IN, bh, bl);
                a2 = MFMA16(A2h[kt], bh, a2);
                a2 = MFMA16(A2l[kt], bh, a2);
                a2 = MFMA16(A2h[kt], bl, a2);
            }
            float p0 = 0.f, p1 = 0.f, p2 = 0.f, p3 = 0.f;
            #pragma unroll
            for (int i = 0; i < 4; ++i) {
                const float h2 = tanhf(fmaf(a2[i], INV_SC, b2v[i]));
                p0 = fmaf(h2, w3v[i][0], p0);
                p1 = fmaf(h2, w3v[i][1], p1);
                p2 = fmaf(h2, w3v[i][2], p2);
                p3 = fmaf(h2, w3v[i][3], p3);
            }
            p0 += __shfl_xor(p0, 16, 64); p0 += __shfl_xor(p0, 32, 64);
            p1 += __shfl_xor(p1, 16, 64); p1 += __shfl_xor(p1, 32, 64);
            p2 += __shfl_xor(p2, 16, 64); p2 += __shfl_xor(p2, 32, 64);
            p3 += __shfl_xor(p3, 16, 64); p3 += __shfl_xor(p3, 32, 64);
            if (lane < 16) {
                const float e0 = expf(p0 + b3v[0]);
                const float e1 = expf(p1 + b3v[1]);
                const float e2 = expf(p2 + b3v[2]);
                const float e3 = expf(p3 + b3v[3]);
                const size_t row = blk_row0 + (size_t)t * TROWS + wid * 16 + lane;
                float4 ev; ev.x = e0; ev.y = e1; ev.z = e2; ev.w = e3;
                *(float4*)(Eout + row * 4) = ev;
                local_sum += (e0 + e1) + (e2 + e3);
            }
        }
    }

    // ---- block exp-sum reduction (deterministic) ----
    #pragma unroll
    for (int off = 32; off > 0; off >>= 1)
        local_sum += __shfl_down(local_sum, off, 64);
    if (lane == 0) sums[wid] = local_sum;
    asm volatile("s_waitcnt lgkmcnt(0)\ns_barrier" ::: "memory");
    if (tid == 0) {
        float s = 0.f;
        #pragma unroll
        for (int w = 0; w < 8; ++w) s += sums[w];
        block_sums[blockIdx.x] = s;
    }
}

// Merged reduce+scale: every block deterministically re-reduces the 256
// partials (1 KiB, L2-hot), then scales its own chunk of E.
__global__ __launch_bounds__(256) void scale_kernel(
    float* __restrict__ out, const float* __restrict__ block_sums)
{
    __shared__ float red[4];
    const int tid = threadIdx.x;
    float s = block_sums[tid];
    #pragma unroll
    for (int off = 32; off > 0; off >>= 1) s += __shfl_down(s, off, 64);
    if ((tid & 63) == 0) red[tid >> 6] = s;
    __syncthreads();
    const float inv = 1.0f / ((red[0] + red[1]) + (red[2] + red[3]));
    const int idx = blockIdx.x * 256 + tid;
    float4* o4 = (float4*)out;
    float4 v = o4[idx];
    v.x *= inv; v.y *= inv; v.z *= inv; v.w *= inv;
    o4[idx] = v;
}

extern "C" void kernel_launch(void* const* d_in, const int* in_sizes, int n_in,
                              void* d_out, int out_size, void* d_ws, size_t ws_size,
                              hipStream_t stream) {
    (void)n_in; (void)ws_size;
    const float* x   = (const float*)d_in[0];
    const float* wz1 = (const float*)d_in[1];
    const float* b1  = (const float*)d_in[2];
    const float* wz2 = (const float*)d_in[3];
    const float* b2  = (const float*)d_in[4];
    const float* wz3 = (const float*)d_in[5];
    const float* b3  = (const float*)d_in[6];
    float* out = (float*)d_out;

    float* block_sums = (float*)d_ws;              // GRID floats

    const int B = in_sizes[0] / 256;               // 262144
    const int ntiles = B / (GRID * TROWS);         // 16

    hipFuncSetAttribute((const void*)fused_mlp,
                        hipFuncAttributeMaxDynamicSharedMemorySize, SMEM_BYTES);

    fused_mlp<<<GRID, TPB, SMEM_BYTES, stream>>>(
        x, wz1, b1, wz2, b2, wz3, b3, out, block_sums, ntiles);

    const int n4 = out_size / 4;                   // 262144
    scale_kernel<<<n4 / 256, 256, 0, stream>>>(out, block_sums);
}

// Round 5
// 57.404 us; speedup vs baseline: 1.1692x; 1.1692x over previous
//
#include <hip/hip_runtime.h>

// B = 262144 rows, 256 -> 64 (relu) -> 16 (tanh) -> 4 -> global softmax.
// Layer 1 & 2 on MFMA f16 with 2-way split operands (3-term products),
// power-of-2 scaled so split residuals stay f16-normal.
// R5: R3 pipeline (convert phase -> f16 LDS -> pure ds_read+MFMA loop),
//     w1 hi AND lo fragments persistent in registers, merged reduce+scale.

typedef _Float16 half8 __attribute__((ext_vector_type(8)));
typedef _Float16 half4 __attribute__((ext_vector_type(4)));
typedef float f32x4 __attribute__((ext_vector_type(4)));

#define GRID 256
#define TPB  512
#define TROWS 64

#define XS  264   // f16 stride for x rows (256 + 8 pad)
#define WS  264   // w1T stride
#define H1S 72    // h1 [row][j] stride (64 + 8)
#define W2S 72    // w2T stride

#define SCALE_IN 256.0f            // 2^8
#define SCALE_W  2048.0f           // 2^11
#define INV_SC   (1.0f/524288.0f)  // 2^-19

// ---- LDS byte offsets (identical to R3) ----
#define OFF_XH  0
#define OFF_XL  (OFF_XH + TROWS*XS*2)      // 33792
#define OFF_W1H (OFF_XL + TROWS*XS*2)      // 67584
#define OFF_W1L (OFF_W1H + 64*WS*2)        // 101376
#define OFF_H1H (OFF_W1L + 64*WS*2)        // 135168
#define OFF_H1L (OFF_H1H + TROWS*H1S*2)    // 144384
#define OFF_W2H (OFF_H1L + TROWS*H1S*2)    // 153600
#define OFF_W2L (OFF_W2H + 16*W2S*2)       // 155904
#define OFF_SUM (OFF_W2L + 16*W2S*2)       // 158208
#define SMEM_BYTES (OFF_SUM + 64*4)        // 158464 <= 163840

extern __shared__ char smem_raw[];

#define MFMA16(a,b,c) __builtin_amdgcn_mfma_f32_16x16x32_f16((a),(b),(c),0,0,0)

__device__ __forceinline__ void lds_barrier() {
    asm volatile("s_waitcnt lgkmcnt(0)\ns_barrier" ::: "memory");
}

__global__ __launch_bounds__(TPB, 2) void fused_mlp(
    const float* __restrict__ x,
    const float* __restrict__ wz1, const float* __restrict__ b1,
    const float* __restrict__ wz2, const float* __restrict__ b2,
    const float* __restrict__ wz3, const float* __restrict__ b3,
    float* __restrict__ Eout, float* __restrict__ block_sums,
    int ntiles)
{
    _Float16* xh  = (_Float16*)(smem_raw + OFF_XH);
    _Float16* xl  = (_Float16*)(smem_raw + OFF_XL);
    _Float16* w1h = (_Float16*)(smem_raw + OFF_W1H);
    _Float16* w1l = (_Float16*)(smem_raw + OFF_W1L);
    _Float16* h1h = (_Float16*)(smem_raw + OFF_H1H);
    _Float16* h1l = (_Float16*)(smem_raw + OFF_H1L);
    _Float16* w2h = (_Float16*)(smem_raw + OFF_W2H);
    _Float16* w2l = (_Float16*)(smem_raw + OFF_W2L);
    float* sums   = (float*)(smem_raw + OFF_SUM);

    const int tid  = threadIdx.x;
    const int lane = tid & 63;
    const int wid  = __builtin_amdgcn_readfirstlane(tid >> 6);
    const int l15  = lane & 15;
    const int g8   = (lane >> 4) * 8;

    const size_t blk_row0 = (size_t)blockIdx.x * ntiles * TROWS;

    // ---- prologue: issue x tile-0 loads first (HBM latency overlap) ----
    float4 xv[8];
    {
        const float4* xg = (const float4*)(x + blk_row0 * 256);
        #pragma unroll
        for (int c = 0; c < 8; ++c) xv[c] = xg[c * TPB + tid];
    }

    // ---- stage w1T as scaled f16 hi/lo (once) ----
    {
        const float4* wg = (const float4*)wz1;   // 4096 float4
        #pragma unroll
        for (int c = 0; c < 8; ++c) {
            const int q = c * TPB + tid;         // 0..4095
            const float4 v = wg[q];
            const int k = q >> 4, n0 = (q & 15) * 4;
            const float vv[4] = {v.x, v.y, v.z, v.w};
            #pragma unroll
            for (int i = 0; i < 4; ++i) {
                const float s = vv[i] * SCALE_W;
                const _Float16 h = (_Float16)s;
                w1h[(n0 + i) * WS + k] = h;
                w1l[(n0 + i) * WS + k] = (_Float16)(s - (float)h);
            }
        }
        if (tid < 256) {                         // w2T: 256 float4
            const float4 v = ((const float4*)wz2)[tid];
            const int k = tid >> 2, c0 = (tid & 3) * 4;
            const float vv[4] = {v.x, v.y, v.z, v.w};
            #pragma unroll
            for (int i = 0; i < 4; ++i) {
                const float s = vv[i] * SCALE_W;
                const _Float16 h = (_Float16)s;
                w2h[(c0 + i) * W2S + k] = h;
                w2l[(c0 + i) * W2S + k] = (_Float16)(s - (float)h);
            }
        }
    }

    // ---- per-lane constants ----
    const int rt  = wid >> 1;                 // rowtile 0..3 (layer 1)
    const int ntp = wid & 1;                  // col-pair 0..1
    const int col0 = (2 * ntp) * 16 + l15;
    const int col1 = (2 * ntp + 1) * 16 + l15;
    const float b1v0 = b1[col0], b1v1 = b1[col1];
    float b2v[4], w3v[4][4];
    #pragma unroll
    for (int i = 0; i < 4; ++i) {
        const int c2 = (lane >> 4) * 4 + i;
        b2v[i] = b2[c2];
        #pragma unroll
        for (int c3 = 0; c3 < 4; ++c3) w3v[i][c3] = wz3[c2 * 4 + c3];
    }
    const float b3v[4] = {b3[0], b3[1], b3[2], b3[3]};

    lds_barrier();   // weights staged

    // ---- persistent register fragments: w1 hi AND lo ----
    half8 Bh[8][2], Bl[8][2];
    #pragma unroll
    for (int kt = 0; kt < 8; ++kt) {
        Bh[kt][0] = *(const half8*)(w1h + col0 * WS + kt * 32 + g8);
        Bh[kt][1] = *(const half8*)(w1h + col1 * WS + kt * 32 + g8);
        Bl[kt][0] = *(const half8*)(w1l + col0 * WS + kt * 32 + g8);
        Bl[kt][1] = *(const half8*)(w1l + col1 * WS + kt * 32 + g8);
    }
    half8 A2h[2], A2l[2];                     // w2T A-frags (layer 2)
    #pragma unroll
    for (int kt = 0; kt < 2; ++kt) {
        A2h[kt] = *(const half8*)(w2h + l15 * W2S + kt * 32 + g8);
        A2l[kt] = *(const half8*)(w2l + l15 * W2S + kt * 32 + g8);
    }

    float local_sum = 0.f;

    for (int t = 0; t < ntiles; ++t) {
        // ---- convert regs -> LDS f16 hi/lo (row = c*8+wid, k = lane*4) ----
        #pragma unroll
        for (int c = 0; c < 8; ++c) {
            const float vv[4] = {xv[c].x, xv[c].y, xv[c].z, xv[c].w};
            half4 hh, hl;
            #pragma unroll
            for (int i = 0; i < 4; ++i) {
                const float s = vv[i] * SCALE_IN;
                const _Float16 h = (_Float16)s;
                hh[i] = h;
                hl[i] = (_Float16)(s - (float)h);
            }
            const int row = c * 8 + wid;
            *(half4*)(xh + row * XS + lane * 4) = hh;
            *(half4*)(xl + row * XS + lane * 4) = hl;
        }
        // ---- issue next-tile global loads (stay in flight across barrier) ----
        if (t + 1 < ntiles) {
            const float4* xg2 =
                (const float4*)(x + (blk_row0 + (size_t)(t + 1) * TROWS) * 256);
            #pragma unroll
            for (int c = 0; c < 8; ++c) xv[c] = xg2[c * TPB + tid];
        }
        lds_barrier();   // B1: x(t) visible

        // ---- layer 1: 3-term split MFMA; A from LDS, B from registers ----
        f32x4 acc0 = {0.f, 0.f, 0.f, 0.f}, acc1 = {0.f, 0.f, 0.f, 0.f};
        {
            const _Float16* xh_p = xh + (rt * 16 + l15) * XS;
            const _Float16* xl_p = xl + (rt * 16 + l15) * XS;
            #pragma unroll
            for (int kt = 0; kt < 8; ++kt) {
                const int ko = kt * 32 + g8;
                const half8 ah = *(const half8*)(xh_p + ko);
                const half8 al = *(const half8*)(xl_p + ko);
                acc0 = MFMA16(ah, Bh[kt][0], acc0);
                acc1 = MFMA16(ah, Bh[kt][1], acc1);
                acc0 = MFMA16(al, Bh[kt][0], acc0);
                acc1 = MFMA16(al, Bh[kt][1], acc1);
                acc0 = MFMA16(ah, Bl[kt][0], acc0);
                acc1 = MFMA16(ah, Bl[kt][1], acc1);
            }
        }
        // ---- epilogue: scale+bias+relu -> h1 f16 hi/lo ----
        #pragma unroll
        for (int i = 0; i < 4; ++i) {
            const int r = rt * 16 + (lane >> 4) * 4 + i;
            const float h0 = fmaxf(fmaf(acc0[i], INV_SC, b1v0), 0.f);
            const float h1f = fmaxf(fmaf(acc1[i], INV_SC, b1v1), 0.f);
            const float s0 = h0 * SCALE_IN;
            const _Float16 h0h = (_Float16)s0;
            h1h[r * H1S + col0] = h0h;
            h1l[r * H1S + col0] = (_Float16)(s0 - (float)h0h);
            const float s1 = h1f * SCALE_IN;
            const _Float16 h1hh = (_Float16)s1;
            h1h[r * H1S + col1] = h1hh;
            h1l[r * H1S + col1] = (_Float16)(s1 - (float)h1hh);
        }
        lds_barrier();   // B2: h1 ready

        // ---- layer 2 (MFMA) + layer 3 + exp: waves 0..3 ----
        if (wid < 4) {
            f32x4 a2 = {0.f, 0.f, 0.f, 0.f};
            const _Float16* hh_p = h1h + (wid * 16 + l15) * H1S;
            const _Float16* hl_p = h1l + (wid * 16 + l15) * H1S;
            #pragma unroll
            for (int kt = 0; kt < 2; ++kt) {
                const int ko = kt * 32 + g8;
                const half8 bh = *(const half8*)(hh_p + ko);
                const half8 bl = *(const half8*)(hl_p + ko);
                a2 = MFMA16(A2h[kt], bh, a2);
                a2 = MFMA16(A2l[kt], bh, a2);
                a2 = MFMA16(A2h[kt], bl, a2);
            }
            // lane holds h2pre for c2 = (lane>>4)*4+i, row = wid*16 + l15
            float p0 = 0.f, p1 = 0.f, p2 = 0.f, p3 = 0.f;
            #pragma unroll
            for (int i = 0; i < 4; ++i) {
                const float h2 = tanhf(fmaf(a2[i], INV_SC, b2v[i]));
                p0 = fmaf(h2, w3v[i][0], p0);
                p1 = fmaf(h2, w3v[i][1], p1);
                p2 = fmaf(h2, w3v[i][2], p2);
                p3 = fmaf(h2, w3v[i][3], p3);
            }
            p0 += __shfl_xor(p0, 16, 64); p0 += __shfl_xor(p0, 32, 64);
            p1 += __shfl_xor(p1, 16, 64); p1 += __shfl_xor(p1, 32, 64);
            p2 += __shfl_xor(p2, 16, 64); p2 += __shfl_xor(p2, 32, 64);
            p3 += __shfl_xor(p3, 16, 64); p3 += __shfl_xor(p3, 32, 64);
            if (lane < 16) {
                const float e0 = expf(p0 + b3v[0]);
                const float e1 = expf(p1 + b3v[1]);
                const float e2 = expf(p2 + b3v[2]);
                const float e3 = expf(p3 + b3v[3]);
                const size_t row = blk_row0 + (size_t)t * TROWS + wid * 16 + lane;
                float4 ev; ev.x = e0; ev.y = e1; ev.z = e2; ev.w = e3;
                *(float4*)(Eout + row * 4) = ev;
                local_sum += (e0 + e1) + (e2 + e3);
            }
        }
    }

    // ---- block exp-sum reduction (deterministic) ----
    #pragma unroll
    for (int off = 32; off > 0; off >>= 1)
        local_sum += __shfl_down(local_sum, off, 64);
    if (lane == 0) sums[wid] = local_sum;
    lds_barrier();
    if (tid == 0) {
        float s = 0.f;
        #pragma unroll
        for (int w = 0; w < 8; ++w) s += sums[w];
        block_sums[blockIdx.x] = s;
    }
}

// Merged reduce+scale: every block deterministically re-reduces the 256
// partials (1 KiB, L2-hot), then scales its own chunk of E.
__global__ __launch_bounds__(256) void scale_kernel(
    float* __restrict__ out, const float* __restrict__ block_sums)
{
    __shared__ float red[4];
    const int tid = threadIdx.x;
    float s = block_sums[tid];
    #pragma unroll
    for (int off = 32; off > 0; off >>= 1) s += __shfl_down(s, off, 64);
    if ((tid & 63) == 0) red[tid >> 6] = s;
    __syncthreads();
    const float inv = 1.0f / ((red[0] + red[1]) + (red[2] + red[3]));
    const int idx = blockIdx.x * 256 + tid;
    float4* o4 = (float4*)out;
    float4 v = o4[idx];
    v.x *= inv; v.y *= inv; v.z *= inv; v.w *= inv;
    o4[idx] = v;
}

extern "C" void kernel_launch(void* const* d_in, const int* in_sizes, int n_in,
                              void* d_out, int out_size, void* d_ws, size_t ws_size,
                              hipStream_t stream) {
    (void)n_in; (void)ws_size;
    const float* x   = (const float*)d_in[0];
    const float* wz1 = (const float*)d_in[1];
    const float* b1  = (const float*)d_in[2];
    const float* wz2 = (const float*)d_in[3];
    const float* b2  = (const float*)d_in[4];
    const float* wz3 = (const float*)d_in[5];
    const float* b3  = (const float*)d_in[6];
    float* out = (float*)d_out;

    float* block_sums = (float*)d_ws;            // GRID floats

    const int B = in_sizes[0] / 256;             // 262144
    const int ntiles = B / (GRID * TROWS);       // 16

    hipFuncSetAttribute((const void*)fused_mlp,
                        hipFuncAttributeMaxDynamicSharedMemorySize, SMEM_BYTES);

    fused_mlp<<<GRID, TPB, SMEM_BYTES, stream>>>(
        x, wz1, b1, wz2, b2, wz3, b3, out, block_sums, ntiles);

    const int n4 = out_size / 4;                 // 262144
    scale_kernel<<<n4 / 256, 256, 0, stream>>>(out, block_sums);
}